// Round 1
// baseline (196.624 us; speedup 1.0000x reference)
//
#include <hip/hip_runtime.h>
#include <math.h>

typedef __bf16 bf16;
typedef __bf16 bf16x8 __attribute__((ext_vector_type(8)));
typedef float f32x4 __attribute__((ext_vector_type(4)));

#define MFMA_BF16(a, b, c) __builtin_amdgcn_mfma_f32_16x16x32_bf16((a), (b), (c), 0, 0, 0)

static constexpr int kB = 2;
static constexpr int kS = 2048;
static constexpr int kD = 512;
static constexpr int kH = 8;
static constexpr int kDK = 64;

// ---------------- mask dtype detection (bool-1B vs int32) ----------------
// int32 0/1 mask: every byte at i%4!=0 is 0. Random bool mask: ~3072 nonzero there.
__global__ void detect_mask_kernel(const unsigned char* __restrict__ m,
                                   unsigned int* __restrict__ flag) {
  __shared__ int sh;
  if (threadIdx.x == 0) sh = 0;
  __syncthreads();
  int any = 0;
  for (int i = threadIdx.x; i < kB * kS; i += 256)
    if ((i & 3) != 0 && m[i] != 0) any = 1;
  if (any) atomicOr(&sh, 1);
  __syncthreads();
  if (threadIdx.x == 0) *flag = (unsigned int)sh;
}

// ---------------- helpers ----------------
__device__ __forceinline__ void cvt16(const float* __restrict__ p, bf16x8& v0, bf16x8& v1) {
  const float4 fA = ((const float4*)p)[0];
  const float4 fB = ((const float4*)p)[1];
  const float4 fC = ((const float4*)p)[2];
  const float4 fD = ((const float4*)p)[3];
  v0[0] = (bf16)fA.x; v0[1] = (bf16)fA.y; v0[2] = (bf16)fA.z; v0[3] = (bf16)fA.w;
  v0[4] = (bf16)fB.x; v0[5] = (bf16)fB.y; v0[6] = (bf16)fB.z; v0[7] = (bf16)fB.w;
  v1[0] = (bf16)fC.x; v1[1] = (bf16)fC.y; v1[2] = (bf16)fC.z; v1[3] = (bf16)fC.w;
  v1[4] = (bf16)fD.x; v1[5] = (bf16)fD.y; v1[6] = (bf16)fD.z; v1[7] = (bf16)fD.w;
}

// ---------------- GEMM: C[m][n] = sum_k A[m][k] * W[n][k] ----------------
// M=4096, N=512, K=512. Tile 128x128, 4 waves computing 64x64 each.
// mode 0/1: store bf16 [b][h][s][dk]; mode 2: store bf16 [b][h][dk][s]; mode 3: f32 [m][n].
template <bool A_IS_F32>
__device__ __forceinline__ void gemm_body(const void* __restrict__ Aptr,
                                          const float* __restrict__ Wptr,
                                          void* __restrict__ dst, const int mode) {
  __shared__ bf16 As[128][40];  // rows padded to 40 elems (80B) - 16B aligned, conflict-light
  __shared__ bf16 Bs[128][40];

  const int tid = threadIdx.x;
  const int lane = tid & 63;
  const int w = tid >> 6;
  const int wr = w >> 1, wc = w & 1;
  const int l16 = lane & 15, g = lane >> 4;

  const int m_tile = blockIdx.x * 128;
  const int n_tile = blockIdx.y * 128;

  f32x4 acc[4][4] = {};

  const int sr = tid >> 1;         // 0..127
  const int sc = (tid & 1) * 16;   // 0 or 16

  for (int k0 = 0; k0 < kD; k0 += 32) {
    // stage A tile (128x32) as bf16
    if constexpr (A_IS_F32) {
      const float* ap = (const float*)Aptr + (size_t)(m_tile + sr) * kD + k0 + sc;
      bf16x8 v0, v1;
      cvt16(ap, v0, v1);
      *(bf16x8*)&As[sr][sc] = v0;
      *(bf16x8*)&As[sr][sc + 8] = v1;
    } else {
      const bf16* ap = (const bf16*)Aptr + (size_t)(m_tile + sr) * kD + k0 + sc;
      *(bf16x8*)&As[sr][sc] = *(const bf16x8*)ap;
      *(bf16x8*)&As[sr][sc + 8] = *(const bf16x8*)(ap + 8);
    }
    // stage W tile (128x32) as bf16
    {
      const float* bp = Wptr + (size_t)(n_tile + sr) * kD + k0 + sc;
      bf16x8 v0, v1;
      cvt16(bp, v0, v1);
      *(bf16x8*)&Bs[sr][sc] = v0;
      *(bf16x8*)&Bs[sr][sc + 8] = v1;
    }
    __syncthreads();

    bf16x8 a[4], bfr[4];
    #pragma unroll
    for (int i = 0; i < 4; i++)
      a[i] = *(const bf16x8*)&As[wr * 64 + i * 16 + l16][g * 8];
    #pragma unroll
    for (int i = 0; i < 4; i++)
      bfr[i] = *(const bf16x8*)&Bs[wc * 64 + i * 16 + l16][g * 8];
    #pragma unroll
    for (int mi = 0; mi < 4; mi++)
      #pragma unroll
      for (int ni = 0; ni < 4; ni++)
        acc[mi][ni] = MFMA_BF16(a[mi], bfr[ni], acc[mi][ni]);
    __syncthreads();
  }

  // epilogue store. C/D frag: col = lane&15, row = (lane>>4)*4 + reg
  #pragma unroll
  for (int mi = 0; mi < 4; mi++) {
    #pragma unroll
    for (int ni = 0; ni < 4; ni++) {
      const int gm0 = m_tile + wr * 64 + mi * 16 + g * 4;
      const int gn = n_tile + wc * 64 + ni * 16 + l16;
      #pragma unroll
      for (int q = 0; q < 4; q++) {
        const int gm = gm0 + q;
        const float v = acc[mi][ni][q];
        if (mode == 3) {
          ((float*)dst)[(size_t)gm * kD + gn] = v;
        } else {
          const int bi = gm >> 11;            // gm / 2048
          const int s = gm & (kS - 1);
          const int h = gn >> 6;              // gn / 64
          const int dk = gn & (kDK - 1);
          if (mode == 2)
            ((bf16*)dst)[(((size_t)bi * kH + h) * kDK + dk) * kS + s] = (bf16)v;
          else
            ((bf16*)dst)[(((size_t)bi * kH + h) * kS + s) * kDK + dk] = (bf16)v;
        }
      }
    }
  }
}

__global__ __launch_bounds__(256) void proj_kernel(
    const float* __restrict__ q, const float* __restrict__ k, const float* __restrict__ v,
    const float* __restrict__ Wq, const float* __restrict__ Wk, const float* __restrict__ Wv,
    bf16* __restrict__ qw, bf16* __restrict__ kw, bf16* __restrict__ vtw) {
  const int z = blockIdx.z;
  const float* A = (z == 0) ? q : (z == 1) ? k : v;
  const float* W = (z == 0) ? Wq : (z == 1) ? Wk : Wv;
  bf16* dstp = (z == 0) ? qw : (z == 1) ? kw : vtw;
  gemm_body<true>(A, W, dstp, (z == 2) ? 2 : 0);
}

__global__ __launch_bounds__(256) void out_kernel(const bf16* __restrict__ x,
                                                  const float* __restrict__ Wo,
                                                  float* __restrict__ out) {
  gemm_body<false>(x, Wo, out, 3);
}

// ---------------- attention ----------------
// grid (S/64, B*H), 256 threads. Wave w handles 16 q-rows. Flash-style over key
// blocks of 64 with online softmax. scores = QK^T/8, mask->-inf, minus bias.
__global__ __launch_bounds__(256) void attn_kernel(
    const bf16* __restrict__ qw, const bf16* __restrict__ kw,
    const bf16* __restrict__ vt, const float* __restrict__ bias,
    const unsigned char* __restrict__ maskp, const unsigned int* __restrict__ flagp,
    bf16* __restrict__ xw) {
  __shared__ bf16 Ks[64][72];      // [key][dk], padded
  __shared__ bf16 Vs[64][72];      // [dk][key], padded
  __shared__ bf16 Ps[4][16][72];   // per-wave P tile [q][key], padded

  const int tid = threadIdx.x;
  const int lane = tid & 63;
  const int w = tid >> 6;
  const int l16 = lane & 15, g = lane >> 4;

  const int bh = blockIdx.y;
  const int b = bh >> 3;
  const int hh = bh & 7;
  const int qr0 = blockIdx.x * 64 + w * 16;

  const bool as_bool = (*flagp != 0u);

  // Q fragments held for whole kernel: A row = lane&15, k = g*8 + j
  const bf16* qrow = qw + ((size_t)bh * kS + qr0 + l16) * kDK;
  const bf16x8 aq0 = *(const bf16x8*)(qrow + g * 8);
  const bf16x8 aq1 = *(const bf16x8*)(qrow + 32 + g * 8);

  f32x4 o[4] = {};
  float m_run[4], l_run[4];
  #pragma unroll
  for (int r = 0; r < 4; r++) { m_run[r] = -__builtin_inff(); l_run[r] = 0.f; }

  const float* bias_base = bias + ((size_t)bh * kS + qr0 + g * 4) * kS;

  const int str = tid >> 2;         // 0..63 staging row
  const int stc = (tid & 3) * 16;   // 0,16,32,48

  for (int k0 = 0; k0 < kS; k0 += 64) {
    __syncthreads();  // previous tile fully consumed
    {
      const bf16* kp = kw + ((size_t)bh * kS + k0 + str) * kDK + stc;
      *(bf16x8*)&Ks[str][stc] = *(const bf16x8*)kp;
      *(bf16x8*)&Ks[str][stc + 8] = *(const bf16x8*)(kp + 8);
      const bf16* vp = vt + ((size_t)bh * kDK + str) * kS + k0 + stc;
      *(bf16x8*)&Vs[str][stc] = *(const bf16x8*)vp;
      *(bf16x8*)&Vs[str][stc + 8] = *(const bf16x8*)(vp + 8);
    }
    __syncthreads();

    // QK^T: rows=q, cols=key
    f32x4 sfr[4];
    #pragma unroll
    for (int nf = 0; nf < 4; nf++) {
      const bf16x8 bk0 = *(const bf16x8*)&Ks[nf * 16 + l16][g * 8];
      const bf16x8 bk1 = *(const bf16x8*)&Ks[nf * 16 + l16][32 + g * 8];
      f32x4 z = {};
      z = MFMA_BF16(aq0, bk0, z);
      z = MFMA_BF16(aq1, bk1, z);
      sfr[nf] = z;
    }

    // scores -> masked, biased; online softmax
    float p[4][4];
    float tmax[4] = {-__builtin_inff(), -__builtin_inff(), -__builtin_inff(), -__builtin_inff()};
    #pragma unroll
    for (int nf = 0; nf < 4; nf++) {
      const int kcol = k0 + nf * 16 + l16;
      const bool msk = as_bool ? (maskp[(size_t)b * kS + kcol] != 0)
                               : (((const int*)maskp)[(size_t)b * kS + kcol] != 0);
      #pragma unroll
      for (int r = 0; r < 4; r++) {
        float sv = sfr[nf][r] * 0.125f - bias_base[(size_t)r * kS + kcol];
        if (msk) sv = -__builtin_inff();
        p[nf][r] = sv;
        tmax[r] = fmaxf(tmax[r], sv);
      }
    }
    #pragma unroll
    for (int mm = 1; mm < 16; mm <<= 1) {
      #pragma unroll
      for (int r = 0; r < 4; r++)
        tmax[r] = fmaxf(tmax[r], __shfl_xor(tmax[r], mm, 64));
    }
    float rsum[4];
    #pragma unroll
    for (int r = 0; r < 4; r++) {
      const float mnew = fmaxf(m_run[r], tmax[r]);
      const float scale = (m_run[r] == -__builtin_inff()) ? 0.f : __expf(m_run[r] - mnew);
      const float mexp = (mnew == -__builtin_inff()) ? 0.f : mnew;
      float ps = 0.f;
      #pragma unroll
      for (int nf = 0; nf < 4; nf++) {
        const float pv = __expf(p[nf][r] - mexp);
        p[nf][r] = pv;
        ps += pv;
      }
      rsum[r] = ps;
      m_run[r] = mnew;
      l_run[r] *= scale;
      #pragma unroll
      for (int ni = 0; ni < 4; ni++) o[ni][r] *= scale;
    }
    #pragma unroll
    for (int mm = 1; mm < 16; mm <<= 1) {
      #pragma unroll
      for (int r = 0; r < 4; r++)
        rsum[r] += __shfl_xor(rsum[r], mm, 64);
    }
    #pragma unroll
    for (int r = 0; r < 4; r++) l_run[r] += rsum[r];

    // P -> LDS (wave-local) for PV A-fragments
    #pragma unroll
    for (int nf = 0; nf < 4; nf++)
      #pragma unroll
      for (int r = 0; r < 4; r++)
        Ps[w][g * 4 + r][nf * 16 + l16] = (bf16)p[nf][r];
    asm volatile("s_waitcnt lgkmcnt(0)" ::: "memory");

    const bf16x8 pa0 = *(const bf16x8*)&Ps[w][l16][g * 8];
    const bf16x8 pa1 = *(const bf16x8*)&Ps[w][l16][32 + g * 8];
    #pragma unroll
    for (int ni = 0; ni < 4; ni++) {
      const bf16x8 bv0 = *(const bf16x8*)&Vs[ni * 16 + l16][g * 8];
      const bf16x8 bv1 = *(const bf16x8*)&Vs[ni * 16 + l16][32 + g * 8];
      o[ni] = MFMA_BF16(pa0, bv0, o[ni]);
      o[ni] = MFMA_BF16(pa1, bv1, o[ni]);
    }
  }

  // epilogue: x[b][s][h*DK+dk] bf16
  #pragma unroll
  for (int r = 0; r < 4; r++) {
    const float inv = (l_run[r] > 0.f) ? 1.f / l_run[r] : 0.f;
    const int srow = qr0 + g * 4 + r;
    bf16* dstp = xw + ((size_t)b * kS + srow) * kD + hh * kDK;
    #pragma unroll
    for (int ni = 0; ni < 4; ni++)
      dstp[ni * 16 + l16] = (bf16)(o[ni][r] * inv);
  }
}

extern "C" void kernel_launch(void* const* d_in, const int* in_sizes, int n_in,
                              void* d_out, int out_size, void* d_ws, size_t ws_size,
                              hipStream_t stream) {
  (void)in_sizes; (void)n_in; (void)out_size; (void)ws_size;
  const float* query = (const float*)d_in[0];
  const float* key_in = (const float*)d_in[1];
  const float* value = (const float*)d_in[2];
  const float* attnw = (const float*)d_in[3];
  const unsigned char* mask = (const unsigned char*)d_in[4];
  const float* Wq = (const float*)d_in[5];
  const float* Wk = (const float*)d_in[6];
  const float* Wv = (const float*)d_in[7];
  const float* Wo = (const float*)d_in[8];

  const size_t nqkv = (size_t)kB * kH * kS * kDK;  // 2M elems
  bf16* q_ws = (bf16*)d_ws;
  bf16* k_ws = q_ws + nqkv;
  bf16* vt_ws = k_ws + nqkv;
  bf16* x_ws = vt_ws + nqkv;
  unsigned int* flagp = (unsigned int*)(x_ws + (size_t)kB * kS * kD);

  detect_mask_kernel<<<1, 256, 0, stream>>>(mask, flagp);

  dim3 blk(256);
  proj_kernel<<<dim3(32, 4, 3), blk, 0, stream>>>(query, key_in, value, Wq, Wk, Wv,
                                                  q_ws, k_ws, vt_ws);
  attn_kernel<<<dim3(kS / 64, kB * kH), blk, 0, stream>>>(q_ws, k_ws, vt_ws, attnw,
                                                          mask, flagp, x_ws);
  out_kernel<<<dim3(32, 4), blk, 0, stream>>>(x_ws, Wo, (float*)d_out);
}